// Round 3
// baseline (3621.111 us; speedup 1.0000x reference)
//
#include <hip/hip_runtime.h>
#include <hip/hip_bf16.h>
#include <math.h>

constexpr int B = 32, S = 64, T = 64, H = 512, V = 32000;
constexpr int G3 = 3 * H;     // 1536
constexpr int BT = B * T;     // 2048

// ---- workspace layout (float offsets) ----
constexpr size_t UAK_OFF    = 0;          // [B*S*H]     1,048,576
constexpr size_t GIE_OFF    = 1048576;    // [B*T*G3]    3,145,728
constexpr size_t KWT_OFF    = 4194304;    // [B*G3*S]    3,145,728
constexpr size_t HALL_OFF   = 7340032;    // [(T+1)*B*H] 1,064,960
constexpr size_t SCP_OFF    = 8404992;    // [B*8*S]     16,384
constexpr size_t ROWIDX_OFF = 8421376;    // 2048 ints
constexpr size_t FLG_OFF    = 8423424;    // 64*32 ints
constexpr size_t HBF_OFF    = 8425472;    // bf16 [B*T*H] = 524,288 float slots
constexpr size_t OWBF_OFF   = 0;          // bf16 [V*H]; aliases UAK/GIE/KWT/HALL[0:51]
                                          // (dead by then; final h row is beyond 8.19M)

typedef __attribute__((ext_vector_type(8))) short bf16x8;
typedef __attribute__((ext_vector_type(4))) float f32x4;

__device__ __forceinline__ float fast_tanh(float x) {
  float ax = fabsf(x);
  float e = __expf(-2.f * ax);
  float r = (1.f - e) / (1.f + e);
  return x < 0.f ? -r : r;
}
__device__ __forceinline__ float fast_sig(float x) {
  return 1.f / (1.f + __expf(-x));
}

// -------------------- init: h0, token row indices, flags --------------------
__global__ void k_init(const float* __restrict__ eh, const int* __restrict__ tgt,
                       float* __restrict__ ws) {
  int i = blockIdx.x * 256 + threadIdx.x;      // grid 64*256 = 16384
  if (i < B * H) ws[HALL_OFF + i] = eh[i];
  if (i < BT) {
    int b = i / T, t = i % T;
    ((int*)(ws + ROWIDX_OFF))[i] = (t == 0) ? 0 : tgt[b * T + t - 1];
  }
  if (i < 64 * 32) ((int*)(ws + FLG_OFF))[i] = 0;
}

// -------------------- out_w fp32 -> bf16 (runs AFTER recurrence; aliases ws) ----
__global__ void k_conv_outw(const float* __restrict__ w, ushort* __restrict__ o, int n4) {
  int i = blockIdx.x * blockDim.x + threadIdx.x;
  if (i < n4) {
    float4 v = *(const float4*)&w[(size_t)i * 4];
    ushort4 u;
    __hip_bfloat16 h0 = __float2bfloat16(v.x); u.x = *(ushort*)&h0;
    __hip_bfloat16 h1 = __float2bfloat16(v.y); u.y = *(ushort*)&h1;
    __hip_bfloat16 h2 = __float2bfloat16(v.z); u.z = *(ushort*)&h2;
    __hip_bfloat16 h3 = __float2bfloat16(v.w); u.w = *(ushort*)&h3;
    *(ushort4*)&o[(size_t)i * 4] = u;
  }
}

// -------- fp32 tiled GEMM, k-major LDS: C[m,n] = A[arow(m),:] . Bw[n,:] + bias[n] --------
__global__ __launch_bounds__(256) void k_gemm_at(
    const float* __restrict__ A, const float* __restrict__ Bw, int ldb,
    const float* __restrict__ bias, float* __restrict__ C,
    const int* __restrict__ rowidx, int N) {
  __shared__ float AsT[32][72];
  __shared__ float BsT[32][72];
  int tid = threadIdx.x;
  int bm = blockIdx.x, bn = blockIdx.y;
  int tr = tid >> 4, tc = tid & 15;
  float acc[4][4] = {};
  for (int k0 = 0; k0 < 512; k0 += 32) {
    __syncthreads();
#pragma unroll
    for (int i = 0; i < 2; i++) {
      int e = tid + i * 256;
      int row = e >> 3, c4 = (e & 7) * 4;
      int ar = bm * 64 + row;
      int arow = rowidx ? rowidx[ar] : ar;
      float4 v = *(const float4*)&A[(size_t)arow * 512 + k0 + c4];
      AsT[c4 + 0][row] = v.x; AsT[c4 + 1][row] = v.y;
      AsT[c4 + 2][row] = v.z; AsT[c4 + 3][row] = v.w;
      float4 u = *(const float4*)&Bw[(size_t)(bn * 64 + row) * ldb + k0 + c4];
      BsT[c4 + 0][row] = u.x; BsT[c4 + 1][row] = u.y;
      BsT[c4 + 2][row] = u.z; BsT[c4 + 3][row] = u.w;
    }
    __syncthreads();
#pragma unroll
    for (int kk = 0; kk < 32; kk++) {
      float4 a4 = *(const float4*)&AsT[kk][tr * 4];
      float4 b4 = *(const float4*)&BsT[kk][tc * 4];
      acc[0][0] += a4.x * b4.x; acc[0][1] += a4.x * b4.y; acc[0][2] += a4.x * b4.z; acc[0][3] += a4.x * b4.w;
      acc[1][0] += a4.y * b4.x; acc[1][1] += a4.y * b4.y; acc[1][2] += a4.y * b4.z; acc[1][3] += a4.y * b4.w;
      acc[2][0] += a4.z * b4.x; acc[2][1] += a4.z * b4.y; acc[2][2] += a4.z * b4.z; acc[2][3] += a4.z * b4.w;
      acc[3][0] += a4.w * b4.x; acc[3][1] += a4.w * b4.y; acc[3][2] += a4.w * b4.z; acc[3][3] += a4.w * b4.w;
    }
  }
#pragma unroll
  for (int i = 0; i < 4; i++) {
    int m = bm * 64 + tr * 4 + i;
#pragma unroll
    for (int j = 0; j < 4; j++) {
      int n = bn * 64 + tc * 4 + j;
      C[(size_t)m * N + n] = acc[i][j] + bias[n];
    }
  }
}

// -------- KWT[b, col, s] = sum_k W_ih[col, 512+k] * keys[b*64+s, k] --------
__global__ __launch_bounds__(256) void k_gemm_kwt(
    const float* __restrict__ W_ih, const float* __restrict__ keys,
    float* __restrict__ KWT) {
  __shared__ float AsT[32][72];
  __shared__ float BsT[32][72];
  int tid = threadIdx.x;
  int bm = blockIdx.x, b = blockIdx.y;
  int tr = tid >> 4, tc = tid & 15;
  float acc[4][4] = {};
  for (int k0 = 0; k0 < 512; k0 += 32) {
    __syncthreads();
#pragma unroll
    for (int i = 0; i < 2; i++) {
      int e = tid + i * 256;
      int row = e >> 3, c4 = (e & 7) * 4;
      float4 v = *(const float4*)&W_ih[(size_t)(bm * 64 + row) * 1024 + 512 + k0 + c4];
      AsT[c4 + 0][row] = v.x; AsT[c4 + 1][row] = v.y;
      AsT[c4 + 2][row] = v.z; AsT[c4 + 3][row] = v.w;
      float4 u = *(const float4*)&keys[(size_t)(b * 64 + row) * 512 + k0 + c4];
      BsT[c4 + 0][row] = u.x; BsT[c4 + 1][row] = u.y;
      BsT[c4 + 2][row] = u.z; BsT[c4 + 3][row] = u.w;
    }
    __syncthreads();
#pragma unroll
    for (int kk = 0; kk < 32; kk++) {
      float4 a4 = *(const float4*)&AsT[kk][tr * 4];
      float4 b4 = *(const float4*)&BsT[kk][tc * 4];
      acc[0][0] += a4.x * b4.x; acc[0][1] += a4.x * b4.y; acc[0][2] += a4.x * b4.z; acc[0][3] += a4.x * b4.w;
      acc[1][0] += a4.y * b4.x; acc[1][1] += a4.y * b4.y; acc[1][2] += a4.y * b4.z; acc[1][3] += a4.y * b4.w;
      acc[2][0] += a4.z * b4.x; acc[2][1] += a4.z * b4.y; acc[2][2] += a4.z * b4.z; acc[2][3] += a4.z * b4.w;
      acc[3][0] += a4.w * b4.x; acc[3][1] += a4.w * b4.y; acc[3][2] += a4.w * b4.z; acc[3][3] += a4.w * b4.w;
    }
  }
#pragma unroll
  for (int i = 0; i < 4; i++) {
    int m = bm * 64 + tr * 4 + i;
#pragma unroll
    for (int j = 0; j < 4; j++)
      KWT[((size_t)b * G3 + m) * S + tc * 4 + j] = acc[i][j];
  }
}

// -------------------- merged per-step kernel --------------------
// grid 384: WGs 0..255 = producers (b=wg>>3, g=wg&7): q-slice + tanh-score partials.
// WGs 256..383 = consumers (wp=wg-256): softmax + gates + h-update for hcols wp*4..+4.
// Cross-WG within launch: SCP via sc0sc1 write-through stores + relaxed agent flag adds;
// consumers poll relaxed agent loads (no fences -> caches stay warm), read SCP normally
// (first touch this launch => L2 miss => fresh from coherence point).
__global__ __launch_bounds__(256) void k_step(
    const float* __restrict__ Wa_w, const float* __restrict__ Wa_b,
    const float* __restrict__ Va_w, const float* __restrict__ Va_b,
    const float* __restrict__ W_hh, const float* __restrict__ b_hh,
    float* __restrict__ ws, float* __restrict__ attn_out, int t) {
  const int wg = blockIdx.x;
  const int tid = threadIdx.x;
  const float* hcur = ws + HALL_OFF + (size_t)t * B * H;
  int* flg = (int*)(ws + FLG_OFF) + t * 32;

  __shared__ float sw[32][64];
  __shared__ float g01[2][4][32];
  __shared__ float g2i[4][32];
  __shared__ float g2h[4][32];
  __shared__ float qp[64][4];
  __shared__ float sq[64];
  __shared__ float sp[64][4];

  if (wg < 256) {
    // ================= producer =================
    const int b = wg >> 3, g = wg & 7;
    // q[b, g*64+jl] partial over k-quarter
    {
      int jl = tid >> 2, kq = tid & 3;
      const float* hv = hcur + b * H + kq * 128;
      const float* wv = Wa_w + (size_t)(g * 64 + jl) * H + kq * 128;
      float acc = 0.f;
#pragma unroll
      for (int i = 0; i < 128; i += 4) {
        float4 a4 = *(const float4*)&hv[i];
        float4 w4 = *(const float4*)&wv[i];
        acc += a4.x * w4.x + a4.y * w4.y + a4.z * w4.z + a4.w * w4.w;
      }
      qp[jl][kq] = acc;
    }
    __syncthreads();
    if (tid < 64)
      sq[tid] = qp[tid][0] + qp[tid][1] + qp[tid][2] + qp[tid][3] + Wa_b[g * 64 + tid];
    __syncthreads();
    // partial score over this WG's 64-j slice
    {
      int s = tid >> 2, jc = tid & 3;
      const float* ukp = ws + UAK_OFF + ((size_t)(b * 64 + s)) * H + g * 64 + jc * 16;
      const float* vap = Va_w + g * 64 + jc * 16;
      const float* sqp = &sq[jc * 16];
      float accs = 0.f;
#pragma unroll
      for (int i = 0; i < 16; i += 4) {
        float4 u4 = *(const float4*)&ukp[i];
        float4 v4 = *(const float4*)&vap[i];
        accs += v4.x * fast_tanh(sqp[i] + u4.x) + v4.y * fast_tanh(sqp[i + 1] + u4.y)
              + v4.z * fast_tanh(sqp[i + 2] + u4.z) + v4.w * fast_tanh(sqp[i + 3] + u4.w);
      }
      sp[s][jc] = accs;
    }
    __syncthreads();
    if (tid < 64) {
      float val = sp[tid][0] + sp[tid][1] + sp[tid][2] + sp[tid][3];
      if (g == 0) val += Va_b[0];
      float* dst = ws + SCP_OFF + ((size_t)b * 8 + g) * 64 + tid;
      asm volatile("global_store_dword %0, %1, off sc0 sc1" :: "v"(dst), "v"(val) : "memory");
    }
    if (tid == 0) {
      asm volatile("s_waitcnt vmcnt(0)" ::: "memory");
      __hip_atomic_fetch_add(&flg[wg >> 3], 1, __ATOMIC_RELAXED, __HIP_MEMORY_SCOPE_AGENT);
    }
    return;
  }

  // ================= consumer =================
  const int wp = wg - 256;           // 0..127
  const int j0 = wp * 4;             // 4 h-cols
  float* hnext = ws + HALL_OFF + (size_t)(t + 1) * B * H;
  __hip_bfloat16* HBF = (__hip_bfloat16*)(ws + HBF_OFF);

  if (tid < 32) {
    while (__hip_atomic_load(&flg[tid], __ATOMIC_RELAXED, __HIP_MEMORY_SCOPE_AGENT) != 8)
      __builtin_amdgcn_s_sleep(2);
  }
  __syncthreads();
  // sum the 8 score slices (fixed order -> deterministic); normal cached loads (fresh)
  {
    int b = tid >> 3, sc = tid & 7;
    float s0 = 0, s1 = 0, s2 = 0, s3 = 0, s4 = 0, s5 = 0, s6 = 0, s7 = 0;
#pragma unroll
    for (int g = 0; g < 8; g++) {
      const float* spp = ws + SCP_OFF + ((size_t)b * 8 + g) * 64 + sc * 8;
      float4 v0 = *(const float4*)spp;
      float4 v1 = *(const float4*)(spp + 4);
      s0 += v0.x; s1 += v0.y; s2 += v0.z; s3 += v0.w;
      s4 += v1.x; s5 += v1.y; s6 += v1.z; s7 += v1.w;
    }
    sw[b][sc * 8 + 0] = s0; sw[b][sc * 8 + 1] = s1; sw[b][sc * 8 + 2] = s2; sw[b][sc * 8 + 3] = s3;
    sw[b][sc * 8 + 4] = s4; sw[b][sc * 8 + 5] = s5; sw[b][sc * 8 + 6] = s6; sw[b][sc * 8 + 7] = s7;
  }
  __syncthreads();
  // row softmax: 4 waves x 8 rows
  {
    int lane = tid & 63, wv = tid >> 6;
    for (int b = wv * 8; b < wv * 8 + 8; b++) {
      float v = sw[b][lane];
      float m = v;
      for (int o = 32; o; o >>= 1) m = fmaxf(m, __shfl_xor(m, o, 64));
      float e = __expf(v - m);
      float su = e;
      for (int o = 32; o; o >>= 1) su += __shfl_xor(su, o, 64);
      sw[b][lane] = e / su;
    }
  }
  __syncthreads();
  if (wp < 32 && tid < 64)
    attn_out[((size_t)wp * T + t) * S + tid] = sw[wp][tid];
  // gates: 384 tasks = 12 cols x 32 b
  for (int task = tid; task < 384; task += 256) {
    int c = task >> 5, b = task & 31;
    int gate = c >> 2, jl = c & 3;
    int col = gate * 512 + j0 + jl;
    const float* wr = W_hh + (size_t)col * H;
    const float* hb = hcur + b * H;
    float gh = 0.f;
#pragma unroll 8
    for (int k = 0; k < 512; k += 4) {
      float4 w4 = *(const float4*)&wr[k];
      float4 h4 = *(const float4*)&hb[k];
      gh += w4.x * h4.x + w4.y * h4.y + w4.z * h4.z + w4.w * h4.w;
    }
    gh += b_hh[col];
    const float* kw = ws + KWT_OFF + ((size_t)b * G3 + col) * 64;
    float gic = 0.f;
#pragma unroll
    for (int s4 = 0; s4 < 64; s4 += 4) {
      float4 k4 = *(const float4*)&kw[s4];
      gic += k4.x * sw[b][s4] + k4.y * sw[b][s4 + 1] + k4.z * sw[b][s4 + 2] + k4.w * sw[b][s4 + 3];
    }
    float gi = ws[GIE_OFF + ((size_t)b * T + t) * G3 + col] + gic;
    if (gate == 0) g01[0][jl][b] = gi + gh;
    else if (gate == 1) g01[1][jl][b] = gi + gh;
    else { g2i[jl][b] = gi; g2h[jl][b] = gh; }
  }
  __syncthreads();
  if (tid < 128) {
    int b = tid >> 2, jl = tid & 3;
    float r = fast_sig(g01[0][jl][b]);
    float z = fast_sig(g01[1][jl][b]);
    float n = fast_tanh(g2i[jl][b] + r * g2h[jl][b]);
    float hold = hcur[b * H + j0 + jl];
    float hn = (1.f - z) * n + z * hold;
    hnext[b * H + j0 + jl] = hn;
    HBF[((size_t)b * T + t) * H + j0 + jl] = __float2bfloat16(hn);
  }
}

// -------------------- bf16 MFMA out-projection: [2048,512] x [32000,512]^T --------------------
__global__ __launch_bounds__(256) void k_outgemm(
    const __hip_bfloat16* __restrict__ Abf, const __hip_bfloat16* __restrict__ Bbf,
    const float* __restrict__ bias, float* __restrict__ Cmat) {
  constexpr int LDT = 40;
  __shared__ __align__(16) short As[128 * LDT];
  __shared__ __align__(16) short Bs[128 * LDT];
  int bm = blockIdx.y, bn = blockIdx.x;
  int tid = threadIdx.x;
  int lane = tid & 63, wid = tid >> 6;
  int wm = wid >> 1, wn = wid & 1;
  f32x4 acc[4][4] = {};
  int srow = tid >> 1, shalf = tid & 1;
  for (int k0 = 0; k0 < 512; k0 += 32) {
    const float4* ga = (const float4*)&Abf[(size_t)(bm * 128 + srow) * 512 + k0 + shalf * 16];
    const float4* gb = (const float4*)&Bbf[(size_t)(bn * 128 + srow) * 512 + k0 + shalf * 16];
    float4 va0 = ga[0], va1 = ga[1];
    float4 vb0 = gb[0], vb1 = gb[1];
    __syncthreads();
    *(float4*)&As[srow * LDT + shalf * 16] = va0;
    *(float4*)&As[srow * LDT + shalf * 16 + 8] = va1;
    *(float4*)&Bs[srow * LDT + shalf * 16] = vb0;
    *(float4*)&Bs[srow * LDT + shalf * 16 + 8] = vb1;
    __syncthreads();
    int kc = lane >> 4, rl = lane & 15;
    bf16x8 af[4], bfv[4];
#pragma unroll
    for (int f = 0; f < 4; f++) {
      af[f] = *(const bf16x8*)&As[(wm * 64 + f * 16 + rl) * LDT + kc * 8];
      bfv[f] = *(const bf16x8*)&Bs[(wn * 64 + f * 16 + rl) * LDT + kc * 8];
    }
#pragma unroll
    for (int i = 0; i < 4; i++)
#pragma unroll
      for (int j = 0; j < 4; j++)
        acc[i][j] = __builtin_amdgcn_mfma_f32_16x16x32_bf16(af[i], bfv[j], acc[i][j], 0, 0, 0);
  }
  int cl = lane & 15, rg = lane >> 4;
#pragma unroll
  for (int i = 0; i < 4; i++) {
    int m = bm * 128 + wm * 64 + i * 16 + rg * 4;
#pragma unroll
    for (int j = 0; j < 4; j++) {
      int n = bn * 128 + wn * 64 + j * 16 + cl;
      float bv = bias[n];
#pragma unroll
      for (int r = 0; r < 4; r++)
        Cmat[(size_t)(m + r) * V + n] = acc[i][j][r] + bv;
    }
  }
}

// -------------------- in-place log_softmax (online stats, 2 passes) --------------------
__global__ __launch_bounds__(256) void k_logsoftmax(float* __restrict__ Cmat) {
  int row = blockIdx.x;
  float* p = Cmat + (size_t)row * V;
  int tid = threadIdx.x;
  __shared__ float sm[4], ss[4];
  float m = -1e30f, s = 0.f;
  for (int i = tid * 4; i < V; i += 1024) {
    float4 v = *(const float4*)&p[i];
    float m4 = fmaxf(fmaxf(v.x, v.y), fmaxf(v.z, v.w));
    float nm = fmaxf(m, m4);
    s = s * __expf(m - nm) + __expf(v.x - nm) + __expf(v.y - nm)
      + __expf(v.z - nm) + __expf(v.w - nm);
    m = nm;
  }
  for (int o = 32; o; o >>= 1) {
    float om = __shfl_xor(m, o, 64), os = __shfl_xor(s, o, 64);
    float nm = fmaxf(m, om);
    s = s * __expf(m - nm) + os * __expf(om - nm);
    m = nm;
  }
  if ((tid & 63) == 0) { sm[tid >> 6] = m; ss[tid >> 6] = s; }
  __syncthreads();
  float M = fmaxf(fmaxf(sm[0], sm[1]), fmaxf(sm[2], sm[3]));
  float Ssum = ss[0] * __expf(sm[0] - M) + ss[1] * __expf(sm[1] - M)
             + ss[2] * __expf(sm[2] - M) + ss[3] * __expf(sm[3] - M);
  float lse = M + __logf(Ssum);
  for (int i = tid * 4; i < V; i += 1024) {
    float4 v = *(const float4*)&p[i];
    v.x -= lse; v.y -= lse; v.z -= lse; v.w -= lse;
    *(float4*)&p[i] = v;
  }
}

__global__ void k_copy_ht(const float* __restrict__ hsrc, float* __restrict__ o) {
  int i = blockIdx.x * 256 + threadIdx.x;
  if (i < B * H) o[i] = hsrc[i];
}

extern "C" void kernel_launch(void* const* d_in, const int* in_sizes, int n_in,
                              void* d_out, int out_size, void* d_ws, size_t ws_size,
                              hipStream_t stream) {
  (void)in_sizes; (void)n_in; (void)out_size; (void)ws_size;
  const float* keys = (const float*)d_in[0];
  const float* ehid = (const float*)d_in[1];
  const int* tgt    = (const int*)d_in[2];
  const float* emb  = (const float*)d_in[4];
  const float* Wa_w = (const float*)d_in[5];
  const float* Wa_b = (const float*)d_in[6];
  const float* Ua_w = (const float*)d_in[7];
  const float* Ua_b = (const float*)d_in[8];
  const float* Va_w = (const float*)d_in[9];
  const float* Va_b = (const float*)d_in[10];
  const float* W_ih = (const float*)d_in[11];
  const float* W_hh = (const float*)d_in[12];
  const float* b_ih = (const float*)d_in[13];
  const float* b_hh = (const float*)d_in[14];
  const float* out_w = (const float*)d_in[15];
  const float* out_b = (const float*)d_in[16];
  float* ws = (float*)d_ws;
  float* out = (float*)d_out;
  float* logits = out;                              // [B,T,V]
  float* ht_out = out + (size_t)B * T * V;          // [1,B,H]
  float* attn_out = ht_out + (size_t)B * H;         // [B,T,S]

  hipLaunchKernelGGL(k_init, dim3(64), dim3(256), 0, stream, ehid, tgt, ws);
  // Ua_keys = keys @ Ua_w.T + Ua_b
  hipLaunchKernelGGL(k_gemm_at, dim3(32, 8), dim3(256), 0, stream,
                     keys, Ua_w, 512, Ua_b, ws + UAK_OFF, (const int*)nullptr, 512);
  // Gi_e = emb[tokens] @ W_ih[:, :512].T + b_ih
  hipLaunchKernelGGL(k_gemm_at, dim3(32, 24), dim3(256), 0, stream,
                     emb, W_ih, 1024, b_ih, ws + GIE_OFF, (const int*)(ws + ROWIDX_OFF), G3);
  // KWT[b,col,s] = W_ih_ctx @ keys[b]^T
  hipLaunchKernelGGL(k_gemm_kwt, dim3(24, 32), dim3(256), 0, stream,
                     W_ih, keys, ws + KWT_OFF);
  // serial recurrence: ONE launch per step (in-kernel producer->consumer sync)
  for (int t = 0; t < T; t++) {
    hipLaunchKernelGGL(k_step, dim3(384), dim3(256), 0, stream,
                       Wa_w, Wa_b, Va_w, Va_b, W_hh, b_hh, ws, attn_out, t);
  }
  hipLaunchKernelGGL(k_copy_ht, dim3(64), dim3(256), 0, stream,
                     ws + HALL_OFF + (size_t)T * B * H, ht_out);
  // bf16 out_w copy goes into the (now dead) precompute region
  hipLaunchKernelGGL(k_conv_outw, dim3((V * H / 4 + 255) / 256), dim3(256), 0, stream,
                     out_w, (ushort*)(ws + OWBF_OFF), V * H / 4);
  hipLaunchKernelGGL(k_outgemm, dim3(250, 16), dim3(256), 0, stream,
                     (const __hip_bfloat16*)(ws + HBF_OFF),
                     (const __hip_bfloat16*)(ws + OWBF_OFF), out_b, logits);
  hipLaunchKernelGGL(k_logsoftmax, dim3(BT), dim3(256), 0, stream, logits);
}

// Round 4
// 3217.290 us; speedup vs baseline: 1.1255x; 1.1255x over previous
//
#include <hip/hip_runtime.h>
#include <hip/hip_bf16.h>
#include <math.h>

constexpr int B = 32, S = 64, T = 64, H = 512, V = 32000;
constexpr int G3 = 3 * H;     // 1536
constexpr int BT = B * T;     // 2048

// ---- workspace layout (float offsets) ----
constexpr size_t UAK_OFF    = 0;          // [B*S*H]     1,048,576
constexpr size_t GIE_OFF    = 1048576;    // [B*T*G3]    3,145,728
constexpr size_t KWT_OFF    = 4194304;    // [B*G3*S]    3,145,728
constexpr size_t HALL_OFF   = 7340032;    // [(T+1)*B*H] 1,064,960
constexpr size_t SCP_OFF    = 8404992;    // [B*8*S]     16,384
constexpr size_t ROWIDX_OFF = 8421376;    // 2048 ints
constexpr size_t FLG_OFF    = 8423424;    // 64*32 ints
constexpr size_t HBF_OFF    = 8425472;    // bf16 [B*T*H] = 524,288 float slots
constexpr size_t OWBF_OFF   = 0;          // bf16 [V*H]; aliases UAK/GIE/KWT/HALL[0:51]
                                          // (dead by then; final h row is beyond 8.19M)

typedef __attribute__((ext_vector_type(8))) short bf16x8;
typedef __attribute__((ext_vector_type(4))) float f32x4;

__device__ __forceinline__ float fast_tanh(float x) {
  float ax = fabsf(x);
  float e = __expf(-2.f * ax);
  float r = (1.f - e) / (1.f + e);
  return x < 0.f ? -r : r;
}
__device__ __forceinline__ float fast_sig(float x) {
  return 1.f / (1.f + __expf(-x));
}
// load that bypasses L1 AND L2 (goes to coherence point / LLC)
__device__ __forceinline__ int load_coh_i32(const int* p) {
  int v;
  asm volatile("global_load_dword %0, %1, off sc0 sc1\n\ts_waitcnt vmcnt(0)"
               : "=v"(v) : "v"(p) : "memory");
  return v;
}

// -------------------- init: h0, token row indices, flags --------------------
__global__ void k_init(const float* __restrict__ eh, const int* __restrict__ tgt,
                       float* __restrict__ ws) {
  int i = blockIdx.x * 256 + threadIdx.x;      // grid 64*256 = 16384
  if (i < B * H) ws[HALL_OFF + i] = eh[i];
  if (i < BT) {
    int b = i / T, t = i % T;
    ((int*)(ws + ROWIDX_OFF))[i] = (t == 0) ? 0 : tgt[b * T + t - 1];
  }
  if (i < 64 * 32) ((int*)(ws + FLG_OFF))[i] = 0;
}

// -------------------- out_w fp32 -> bf16 (runs AFTER recurrence; aliases ws) ----
__global__ void k_conv_outw(const float* __restrict__ w, ushort* __restrict__ o, int n4) {
  int i = blockIdx.x * blockDim.x + threadIdx.x;
  if (i < n4) {
    float4 v = *(const float4*)&w[(size_t)i * 4];
    ushort4 u;
    __hip_bfloat16 h0 = __float2bfloat16(v.x); u.x = *(ushort*)&h0;
    __hip_bfloat16 h1 = __float2bfloat16(v.y); u.y = *(ushort*)&h1;
    __hip_bfloat16 h2 = __float2bfloat16(v.z); u.z = *(ushort*)&h2;
    __hip_bfloat16 h3 = __float2bfloat16(v.w); u.w = *(ushort*)&h3;
    *(ushort4*)&o[(size_t)i * 4] = u;
  }
}

// -------- fp32 tiled GEMM, k-major LDS: C[m,n] = A[arow(m),:] . Bw[n,:] + bias[n] --------
__global__ __launch_bounds__(256) void k_gemm_at(
    const float* __restrict__ A, const float* __restrict__ Bw, int ldb,
    const float* __restrict__ bias, float* __restrict__ C,
    const int* __restrict__ rowidx, int N) {
  __shared__ float AsT[32][72];
  __shared__ float BsT[32][72];
  int tid = threadIdx.x;
  int bm = blockIdx.x, bn = blockIdx.y;
  int tr = tid >> 4, tc = tid & 15;
  float acc[4][4] = {};
  for (int k0 = 0; k0 < 512; k0 += 32) {
    __syncthreads();
#pragma unroll
    for (int i = 0; i < 2; i++) {
      int e = tid + i * 256;
      int row = e >> 3, c4 = (e & 7) * 4;
      int ar = bm * 64 + row;
      int arow = rowidx ? rowidx[ar] : ar;
      float4 v = *(const float4*)&A[(size_t)arow * 512 + k0 + c4];
      AsT[c4 + 0][row] = v.x; AsT[c4 + 1][row] = v.y;
      AsT[c4 + 2][row] = v.z; AsT[c4 + 3][row] = v.w;
      float4 u = *(const float4*)&Bw[(size_t)(bn * 64 + row) * ldb + k0 + c4];
      BsT[c4 + 0][row] = u.x; BsT[c4 + 1][row] = u.y;
      BsT[c4 + 2][row] = u.z; BsT[c4 + 3][row] = u.w;
    }
    __syncthreads();
#pragma unroll
    for (int kk = 0; kk < 32; kk++) {
      float4 a4 = *(const float4*)&AsT[kk][tr * 4];
      float4 b4 = *(const float4*)&BsT[kk][tc * 4];
      acc[0][0] += a4.x * b4.x; acc[0][1] += a4.x * b4.y; acc[0][2] += a4.x * b4.z; acc[0][3] += a4.x * b4.w;
      acc[1][0] += a4.y * b4.x; acc[1][1] += a4.y * b4.y; acc[1][2] += a4.y * b4.z; acc[1][3] += a4.y * b4.w;
      acc[2][0] += a4.z * b4.x; acc[2][1] += a4.z * b4.y; acc[2][2] += a4.z * b4.z; acc[2][3] += a4.z * b4.w;
      acc[3][0] += a4.w * b4.x; acc[3][1] += a4.w * b4.y; acc[3][2] += a4.w * b4.z; acc[3][3] += a4.w * b4.w;
    }
  }
#pragma unroll
  for (int i = 0; i < 4; i++) {
    int m = bm * 64 + tr * 4 + i;
#pragma unroll
    for (int j = 0; j < 4; j++) {
      int n = bn * 64 + tc * 4 + j;
      C[(size_t)m * N + n] = acc[i][j] + bias[n];
    }
  }
}

// -------- KWT[b, col, s] = sum_k W_ih[col, 512+k] * keys[b*64+s, k] --------
__global__ __launch_bounds__(256) void k_gemm_kwt(
    const float* __restrict__ W_ih, const float* __restrict__ keys,
    float* __restrict__ KWT) {
  __shared__ float AsT[32][72];
  __shared__ float BsT[32][72];
  int tid = threadIdx.x;
  int bm = blockIdx.x, b = blockIdx.y;
  int tr = tid >> 4, tc = tid & 15;
  float acc[4][4] = {};
  for (int k0 = 0; k0 < 512; k0 += 32) {
    __syncthreads();
#pragma unroll
    for (int i = 0; i < 2; i++) {
      int e = tid + i * 256;
      int row = e >> 3, c4 = (e & 7) * 4;
      float4 v = *(const float4*)&W_ih[(size_t)(bm * 64 + row) * 1024 + 512 + k0 + c4];
      AsT[c4 + 0][row] = v.x; AsT[c4 + 1][row] = v.y;
      AsT[c4 + 2][row] = v.z; AsT[c4 + 3][row] = v.w;
      float4 u = *(const float4*)&keys[(size_t)(b * 64 + row) * 512 + k0 + c4];
      BsT[c4 + 0][row] = u.x; BsT[c4 + 1][row] = u.y;
      BsT[c4 + 2][row] = u.z; BsT[c4 + 3][row] = u.w;
    }
    __syncthreads();
#pragma unroll
    for (int kk = 0; kk < 32; kk++) {
      float4 a4 = *(const float4*)&AsT[kk][tr * 4];
      float4 b4 = *(const float4*)&BsT[kk][tc * 4];
      acc[0][0] += a4.x * b4.x; acc[0][1] += a4.x * b4.y; acc[0][2] += a4.x * b4.z; acc[0][3] += a4.x * b4.w;
      acc[1][0] += a4.y * b4.x; acc[1][1] += a4.y * b4.y; acc[1][2] += a4.y * b4.z; acc[1][3] += a4.y * b4.w;
      acc[2][0] += a4.z * b4.x; acc[2][1] += a4.z * b4.y; acc[2][2] += a4.z * b4.z; acc[2][3] += a4.z * b4.w;
      acc[3][0] += a4.w * b4.x; acc[3][1] += a4.w * b4.y; acc[3][2] += a4.w * b4.z; acc[3][3] += a4.w * b4.w;
    }
  }
#pragma unroll
  for (int i = 0; i < 4; i++) {
    int m = bm * 64 + tr * 4 + i;
#pragma unroll
    for (int j = 0; j < 4; j++)
      KWT[((size_t)b * G3 + m) * S + tc * 4 + j] = acc[i][j];
  }
}

// -------------------- merged per-step kernel --------------------
// grid 384: WGs 0..255 = producers (b=wg>>3, g=wg&7): q-slice + tanh-score partials,
// write SCP via sc0sc1 (through to LLC), then agent-scope flag add.
// WGs 256..383 = consumers (wp): FIRST compute gh = W_hh.h (independent of scores),
// THEN poll flags with sc0sc1 loads (L2-bypassing -> no stale-line spin),
// then softmax + KWT dots + GRU update for hcols wp*4..+4.
__global__ __launch_bounds__(256) void k_step(
    const float* __restrict__ Wa_w, const float* __restrict__ Wa_b,
    const float* __restrict__ Va_w, const float* __restrict__ Va_b,
    const float* __restrict__ W_hh, const float* __restrict__ b_hh,
    float* __restrict__ ws, float* __restrict__ attn_out, int t) {
  const int wg = blockIdx.x;
  const int tid = threadIdx.x;
  const float* hcur = ws + HALL_OFF + (size_t)t * B * H;
  int* flg = (int*)(ws + FLG_OFF) + t * 32;

  __shared__ float sw[32][64];
  __shared__ float g01[2][4][32];
  __shared__ float g2i[4][32];
  __shared__ float g2h[4][32];
  __shared__ float qp[64][4];
  __shared__ float sq[64];
  __shared__ float sp[64][4];

  if (wg < 256) {
    // ================= producer =================
    const int b = wg >> 3, g = wg & 7;
    {
      int jl = tid >> 2, kq = tid & 3;
      const float* hv = hcur + b * H + kq * 128;
      const float* wv = Wa_w + (size_t)(g * 64 + jl) * H + kq * 128;
      float acc = 0.f;
#pragma unroll
      for (int i = 0; i < 128; i += 4) {
        float4 a4 = *(const float4*)&hv[i];
        float4 w4 = *(const float4*)&wv[i];
        acc += a4.x * w4.x + a4.y * w4.y + a4.z * w4.z + a4.w * w4.w;
      }
      qp[jl][kq] = acc;
    }
    __syncthreads();
    if (tid < 64)
      sq[tid] = qp[tid][0] + qp[tid][1] + qp[tid][2] + qp[tid][3] + Wa_b[g * 64 + tid];
    __syncthreads();
    {
      int s = tid >> 2, jc = tid & 3;
      const float* ukp = ws + UAK_OFF + ((size_t)(b * 64 + s)) * H + g * 64 + jc * 16;
      const float* vap = Va_w + g * 64 + jc * 16;
      const float* sqp = &sq[jc * 16];
      float accs = 0.f;
#pragma unroll
      for (int i = 0; i < 16; i += 4) {
        float4 u4 = *(const float4*)&ukp[i];
        float4 v4 = *(const float4*)&vap[i];
        accs += v4.x * fast_tanh(sqp[i] + u4.x) + v4.y * fast_tanh(sqp[i + 1] + u4.y)
              + v4.z * fast_tanh(sqp[i + 2] + u4.z) + v4.w * fast_tanh(sqp[i + 3] + u4.w);
      }
      sp[s][jc] = accs;
    }
    __syncthreads();
    if (tid < 64) {
      float val = sp[tid][0] + sp[tid][1] + sp[tid][2] + sp[tid][3];
      if (g == 0) val += Va_b[0];
      float* dst = ws + SCP_OFF + ((size_t)b * 8 + g) * 64 + tid;
      asm volatile("global_store_dword %0, %1, off sc0 sc1" :: "v"(dst), "v"(val) : "memory");
    }
    if (tid == 0) {
      asm volatile("s_waitcnt vmcnt(0)" ::: "memory");
      __hip_atomic_fetch_add(&flg[wg >> 3], 1, __ATOMIC_RELAXED, __HIP_MEMORY_SCOPE_AGENT);
    }
    return;
  }

  // ================= consumer =================
  const int wp = wg - 256;           // 0..127
  const int j0 = wp * 4;             // 4 h-cols
  float* hnext = ws + HALL_OFF + (size_t)(t + 1) * B * H;
  __hip_bfloat16* HBF = (__hip_bfloat16*)(ws + HBF_OFF);

  // --- pre-phase (independent of scores): gh = W_hh . h + b_hh ---
  // 384 tasks = 12 cols x 32 b; thread handles task tid and (tid<128) task tid+256.
  float gh0, gh1 = 0.f;
  {
    int c = tid >> 5, b = tid & 31;
    int col = (c >> 2) * 512 + j0 + (c & 3);
    const float* wr = W_hh + (size_t)col * H;
    const float* hb = hcur + b * H;
    float acc = 0.f;
#pragma unroll 8
    for (int k = 0; k < 512; k += 4) {
      float4 w4 = *(const float4*)&wr[k];
      float4 h4 = *(const float4*)&hb[k];
      acc += w4.x * h4.x + w4.y * h4.y + w4.z * h4.z + w4.w * h4.w;
    }
    gh0 = acc + b_hh[col];
  }
  if (tid < 128) {
    int c = 8 + (tid >> 5), b = tid & 31;
    int col = (c >> 2) * 512 + j0 + (c & 3);
    const float* wr = W_hh + (size_t)col * H;
    const float* hb = hcur + b * H;
    float acc = 0.f;
#pragma unroll 8
    for (int k = 0; k < 512; k += 4) {
      float4 w4 = *(const float4*)&wr[k];
      float4 h4 = *(const float4*)&hb[k];
      acc += w4.x * h4.x + w4.y * h4.y + w4.z * h4.z + w4.w * h4.w;
    }
    gh1 = acc + b_hh[col];
  }

  // --- wait for producers: L2-BYPASSING poll (sc0 sc1) ---
  if (tid < 32) {
    while (load_coh_i32(&flg[tid]) != 8)
      __builtin_amdgcn_s_sleep(1);
  }
  __syncthreads();
  // sum the 8 score slices (fixed order -> deterministic).
  // Normal cached loads are safe: first touch of SCP lines this launch -> L2 miss
  // -> fetched from LLC where producers wrote through.
  {
    int b = tid >> 3, sc = tid & 7;
    float s0 = 0, s1 = 0, s2 = 0, s3 = 0, s4 = 0, s5 = 0, s6 = 0, s7 = 0;
#pragma unroll
    for (int g = 0; g < 8; g++) {
      const float* spp = ws + SCP_OFF + ((size_t)b * 8 + g) * 64 + sc * 8;
      float4 v0 = *(const float4*)spp;
      float4 v1 = *(const float4*)(spp + 4);
      s0 += v0.x; s1 += v0.y; s2 += v0.z; s3 += v0.w;
      s4 += v1.x; s5 += v1.y; s6 += v1.z; s7 += v1.w;
    }
    sw[b][sc * 8 + 0] = s0; sw[b][sc * 8 + 1] = s1; sw[b][sc * 8 + 2] = s2; sw[b][sc * 8 + 3] = s3;
    sw[b][sc * 8 + 4] = s4; sw[b][sc * 8 + 5] = s5; sw[b][sc * 8 + 6] = s6; sw[b][sc * 8 + 7] = s7;
  }
  __syncthreads();
  // row softmax: 4 waves x 8 rows
  {
    int lane = tid & 63, wv = tid >> 6;
    for (int b = wv * 8; b < wv * 8 + 8; b++) {
      float v = sw[b][lane];
      float m = v;
      for (int o = 32; o; o >>= 1) m = fmaxf(m, __shfl_xor(m, o, 64));
      float e = __expf(v - m);
      float su = e;
      for (int o = 32; o; o >>= 1) su += __shfl_xor(su, o, 64);
      sw[b][lane] = e / su;
    }
  }
  __syncthreads();
  if (wp < 32 && tid < 64)
    attn_out[((size_t)wp * T + t) * S + tid] = sw[wp][tid];
  // combine: gi_ctx (KWT dot) + GIE + gh -> gate LDS
  {
    int c = tid >> 5, b = tid & 31;
    int gate = c >> 2, jl = c & 3;
    int col = gate * 512 + j0 + jl;
    const float* kw = ws + KWT_OFF + ((size_t)b * G3 + col) * 64;
    float gic = 0.f;
#pragma unroll
    for (int s4 = 0; s4 < 64; s4 += 4) {
      float4 k4 = *(const float4*)&kw[s4];
      gic += k4.x * sw[b][s4] + k4.y * sw[b][s4 + 1] + k4.z * sw[b][s4 + 2] + k4.w * sw[b][s4 + 3];
    }
    float gi = ws[GIE_OFF + ((size_t)b * T + t) * G3 + col] + gic;
    if (gate == 0) g01[0][jl][b] = gi + gh0;
    else if (gate == 1) g01[1][jl][b] = gi + gh0;
    else { g2i[jl][b] = gi; g2h[jl][b] = gh0; }
  }
  if (tid < 128) {
    int c = 8 + (tid >> 5), b = tid & 31;
    int jl = c & 3;                      // gate == 2 always here
    int col = 2 * 512 + j0 + jl;
    const float* kw = ws + KWT_OFF + ((size_t)b * G3 + col) * 64;
    float gic = 0.f;
#pragma unroll
    for (int s4 = 0; s4 < 64; s4 += 4) {
      float4 k4 = *(const float4*)&kw[s4];
      gic += k4.x * sw[b][s4] + k4.y * sw[b][s4 + 1] + k4.z * sw[b][s4 + 2] + k4.w * sw[b][s4 + 3];
    }
    float gi = ws[GIE_OFF + ((size_t)b * T + t) * G3 + col] + gic;
    g2i[jl][b] = gi; g2h[jl][b] = gh1;
  }
  __syncthreads();
  if (tid < 128) {
    int b = tid >> 2, jl = tid & 3;
    float r = fast_sig(g01[0][jl][b]);
    float z = fast_sig(g01[1][jl][b]);
    float n = fast_tanh(g2i[jl][b] + r * g2h[jl][b]);
    float hold = hcur[b * H + j0 + jl];
    float hn = (1.f - z) * n + z * hold;
    hnext[b * H + j0 + jl] = hn;
    HBF[((size_t)b * T + t) * H + j0 + jl] = __float2bfloat16(hn);
  }
}

// -------------------- bf16 MFMA out-projection: [2048,512] x [32000,512]^T --------------------
__global__ __launch_bounds__(256) void k_outgemm(
    const __hip_bfloat16* __restrict__ Abf, const __hip_bfloat16* __restrict__ Bbf,
    const float* __restrict__ bias, float* __restrict__ Cmat) {
  constexpr int LDT = 40;
  __shared__ __align__(16) short As[128 * LDT];
  __shared__ __align__(16) short Bs[128 * LDT];
  int bm = blockIdx.y, bn = blockIdx.x;
  int tid = threadIdx.x;
  int lane = tid & 63, wid = tid >> 6;
  int wm = wid >> 1, wn = wid & 1;
  f32x4 acc[4][4] = {};
  int srow = tid >> 1, shalf = tid & 1;
  for (int k0 = 0; k0 < 512; k0 += 32) {
    const float4* ga = (const float4*)&Abf[(size_t)(bm * 128 + srow) * 512 + k0 + shalf * 16];
    const float4* gb = (const float4*)&Bbf[(size_t)(bn * 128 + srow) * 512 + k0 + shalf * 16];
    float4 va0 = ga[0], va1 = ga[1];
    float4 vb0 = gb[0], vb1 = gb[1];
    __syncthreads();
    *(float4*)&As[srow * LDT + shalf * 16] = va0;
    *(float4*)&As[srow * LDT + shalf * 16 + 8] = va1;
    *(float4*)&Bs[srow * LDT + shalf * 16] = vb0;
    *(float4*)&Bs[srow * LDT + shalf * 16 + 8] = vb1;
    __syncthreads();
    int kc = lane >> 4, rl = lane & 15;
    bf16x8 af[4], bfv[4];
#pragma unroll
    for (int f = 0; f < 4; f++) {
      af[f] = *(const bf16x8*)&As[(wm * 64 + f * 16 + rl) * LDT + kc * 8];
      bfv[f] = *(const bf16x8*)&Bs[(wn * 64 + f * 16 + rl) * LDT + kc * 8];
    }
#pragma unroll
    for (int i = 0; i < 4; i++)
#pragma unroll
      for (int j = 0; j < 4; j++)
        acc[i][j] = __builtin_amdgcn_mfma_f32_16x16x32_bf16(af[i], bfv[j], acc[i][j], 0, 0, 0);
  }
  int cl = lane & 15, rg = lane >> 4;
#pragma unroll
  for (int i = 0; i < 4; i++) {
    int m = bm * 128 + wm * 64 + i * 16 + rg * 4;
#pragma unroll
    for (int j = 0; j < 4; j++) {
      int n = bn * 128 + wn * 64 + j * 16 + cl;
      float bv = bias[n];
#pragma unroll
      for (int r = 0; r < 4; r++)
        Cmat[(size_t)(m + r) * V + n] = acc[i][j][r] + bv;
    }
  }
}

// -------------------- in-place log_softmax (online stats, 2 passes) --------------------
__global__ __launch_bounds__(256) void k_logsoftmax(float* __restrict__ Cmat) {
  int row = blockIdx.x;
  float* p = Cmat + (size_t)row * V;
  int tid = threadIdx.x;
  __shared__ float sm[4], ss[4];
  float m = -1e30f, s = 0.f;
  for (int i = tid * 4; i < V; i += 1024) {
    float4 v = *(const float4*)&p[i];
    float m4 = fmaxf(fmaxf(v.x, v.y), fmaxf(v.z, v.w));
    float nm = fmaxf(m, m4);
    s = s * __expf(m - nm) + __expf(v.x - nm) + __expf(v.y - nm)
      + __expf(v.z - nm) + __expf(v.w - nm);
    m = nm;
  }
  for (int o = 32; o; o >>= 1) {
    float om = __shfl_xor(m, o, 64), os = __shfl_xor(s, o, 64);
    float nm = fmaxf(m, om);
    s = s * __expf(m - nm) + os * __expf(om - nm);
    m = nm;
  }
  if ((tid & 63) == 0) { sm[tid >> 6] = m; ss[tid >> 6] = s; }
  __syncthreads();
  float M = fmaxf(fmaxf(sm[0], sm[1]), fmaxf(sm[2], sm[3]));
  float Ssum = ss[0] * __expf(sm[0] - M) + ss[1] * __expf(sm[1] - M)
             + ss[2] * __expf(sm[2] - M) + ss[3] * __expf(sm[3] - M);
  float lse = M + __logf(Ssum);
  for (int i = tid * 4; i < V; i += 1024) {
    float4 v = *(const float4*)&p[i];
    v.x -= lse; v.y -= lse; v.z -= lse; v.w -= lse;
    *(float4*)&p[i] = v;
  }
}

__global__ void k_copy_ht(const float* __restrict__ hsrc, float* __restrict__ o) {
  int i = blockIdx.x * 256 + threadIdx.x;
  if (i < B * H) o[i] = hsrc[i];
}

extern "C" void kernel_launch(void* const* d_in, const int* in_sizes, int n_in,
                              void* d_out, int out_size, void* d_ws, size_t ws_size,
                              hipStream_t stream) {
  (void)in_sizes; (void)n_in; (void)out_size; (void)ws_size;
  const float* keys = (const float*)d_in[0];
  const float* ehid = (const float*)d_in[1];
  const int* tgt    = (const int*)d_in[2];
  const float* emb  = (const float*)d_in[4];
  const float* Wa_w = (const float*)d_in[5];
  const float* Wa_b = (const float*)d_in[6];
  const float* Ua_w = (const float*)d_in[7];
  const float* Ua_b = (const float*)d_in[8];
  const float* Va_w = (const float*)d_in[9];
  const float* Va_b = (const float*)d_in[10];
  const float* W_ih = (const float*)d_in[11];
  const float* W_hh = (const float*)d_in[12];
  const float* b_ih = (const float*)d_in[13];
  const float* b_hh = (const float*)d_in[14];
  const float* out_w = (const float*)d_in[15];
  const float* out_b = (const float*)d_in[16];
  float* ws = (float*)d_ws;
  float* out = (float*)d_out;
  float* logits = out;                              // [B,T,V]
  float* ht_out = out + (size_t)B * T * V;          // [1,B,H]
  float* attn_out = ht_out + (size_t)B * H;         // [B,T,S]

  hipLaunchKernelGGL(k_init, dim3(64), dim3(256), 0, stream, ehid, tgt, ws);
  // Ua_keys = keys @ Ua_w.T + Ua_b
  hipLaunchKernelGGL(k_gemm_at, dim3(32, 8), dim3(256), 0, stream,
                     keys, Ua_w, 512, Ua_b, ws + UAK_OFF, (const int*)nullptr, 512);
  // Gi_e = emb[tokens] @ W_ih[:, :512].T + b_ih
  hipLaunchKernelGGL(k_gemm_at, dim3(32, 24), dim3(256), 0, stream,
                     emb, W_ih, 1024, b_ih, ws + GIE_OFF, (const int*)(ws + ROWIDX_OFF), G3);
  // KWT[b,col,s] = W_ih_ctx @ keys[b]^T
  hipLaunchKernelGGL(k_gemm_kwt, dim3(24, 32), dim3(256), 0, stream,
                     W_ih, keys, ws + KWT_OFF);
  // serial recurrence: ONE launch per step (in-kernel producer->consumer sync)
  for (int t = 0; t < T; t++) {
    hipLaunchKernelGGL(k_step, dim3(384), dim3(256), 0, stream,
                       Wa_w, Wa_b, Va_w, Va_b, W_hh, b_hh, ws, attn_out, t);
  }
  hipLaunchKernelGGL(k_copy_ht, dim3(64), dim3(256), 0, stream,
                     ws + HALL_OFF + (size_t)T * B * H, ht_out);
  // bf16 out_w copy goes into the (now dead) precompute region
  hipLaunchKernelGGL(k_conv_outw, dim3((V * H / 4 + 255) / 256), dim3(256), 0, stream,
                     out_w, (ushort*)(ws + OWBF_OFF), V * H / 4);
  hipLaunchKernelGGL(k_outgemm, dim3(250, 16), dim3(256), 0, stream,
                     (const __hip_bfloat16*)(ws + HBF_OFF),
                     (const __hip_bfloat16*)(ws + OWBF_OFF), out_b, logits);
  hipLaunchKernelGGL(k_logsoftmax, dim3(BT), dim3(256), 0, stream, logits);
}